// Round 12
// baseline (219.562 us; speedup 1.0000x reference)
//
#include <hip/hip_runtime.h>
#include <math.h>

#define NB 65536
#define ND 1280
#define NH 512
#define NT 4

typedef float f32x4 __attribute__((ext_vector_type(4)));
typedef float f32x2 __attribute__((ext_vector_type(2)));
typedef short s16x8 __attribute__((ext_vector_type(8)));
typedef unsigned int u32x2 __attribute__((ext_vector_type(2)));
typedef unsigned int u32x4 __attribute__((ext_vector_type(4)));
typedef unsigned long long ull;
typedef unsigned short u16;

static __device__ __forceinline__ unsigned f2bf1(float x) {
    union { float f; unsigned u; } v; v.f = x;
    return (v.u + 0x7fffu + ((v.u >> 16) & 1u)) >> 16;   // RNE f32 -> bf16 bits
}
static __device__ __forceinline__ unsigned packbf(float a, float b) {
    return f2bf1(a) | (f2bf1(b) << 16);
}
static __device__ __forceinline__ int swz(int a) {
    return a ^ (((a >> 7) & 7) << 4);
}
static __device__ __forceinline__ float gelu_exact(float x) {
    return 0.5f * x * (1.0f + erff(x * 0.70710678118654752f));
}
static __device__ __forceinline__ void gload_lds16(const void* g, void* l) {
    __builtin_amdgcn_global_load_lds(
        (const __attribute__((address_space(1))) unsigned int*)g,
        (__attribute__((address_space(3))) unsigned int*)l, 16, 0, 0);
}

#define SCHEDB __builtin_amdgcn_sched_barrier(0)
#define WAITVM(N) do { asm volatile("s_waitcnt vmcnt(" #N ")" ::: "memory"); SCHEDB; } while (0)
#define WAITLGKM do { asm volatile("s_waitcnt lgkmcnt(0)" ::: "memory"); SCHEDB; } while (0)

// ---------------- W1 transpose+convert: [t][d][h] f32 -> [t][h][d] bf16 ----------------
__global__ __launch_bounds__(256) void transpose_kernel(const float* __restrict__ W1,
                                                        u16* __restrict__ Wt) {
    __shared__ float tile[64][65];
    int b = blockIdx.x;                 // 4 * 8 * 20 blocks
    int dt = b % 20; int r = b / 20; int ht = r & 7; int t = r >> 3;
    int d0 = dt * 64, h0 = ht * 64;
    int tid = threadIdx.x;
    const float* src = W1 + ((size_t)t * ND + d0) * NH + h0;
#pragma unroll
    for (int it = 0; it < 16; ++it) {
        int dl = it * 4 + (tid >> 6);
        tile[dl][tid & 63] = src[(size_t)dl * NH + (tid & 63)];
    }
    __syncthreads();
    int hl = tid >> 2, ds = (tid & 3) * 16;
    unsigned pk[8];
#pragma unroll
    for (int j = 0; j < 8; ++j)
        pk[j] = packbf(tile[ds + 2 * j][hl], tile[ds + 2 * j + 1][hl]);
    u16* dst = Wt + ((size_t)(t * NH + h0 + hl)) * ND + d0 + ds;
    *(u32x4*)dst = (u32x4){pk[0], pk[1], pk[2], pk[3]};
    *(u32x4*)(dst + 8) = (u32x4){pk[4], pk[5], pk[6], pk[7]};
}

// ---------------- bucketing (atomic-free counting sort) ----------------
__global__ __launch_bounds__(256) void count_kernel(const int* __restrict__ idx,
                                                    int* __restrict__ bc) {
    int tid = threadIdx.x;
    int i = blockIdx.x * 256 + tid;
    int t = idx[i];
    int lane = tid & 63, wave = tid >> 6;
    ull b0 = __ballot(t & 1);
    ull b1 = __ballot(t & 2);
    ull mask = ((t & 1) ? b0 : ~b0) & ((t & 2) ? b1 : ~b1);
    int rank = __popcll(mask & ((1ULL << lane) - 1ULL));
    __shared__ int lc[4][4];
    if (tid < 16) ((int*)lc)[tid] = 0;
    __syncthreads();
    if (rank == 0) lc[wave][t] = __popcll(mask);
    __syncthreads();
    if (tid < 4)
        bc[blockIdx.x * 4 + tid] = lc[0][tid] + lc[1][tid] + lc[2][tid] + lc[3][tid];
}

__global__ __launch_bounds__(256) void scan_kernel(const int* __restrict__ bc,
        int* __restrict__ counts, int* __restrict__ base, int* __restrict__ tmap) {
    // 256 threads -> (seg = tid>>2 in 0..63, t = tid&3); each seg covers 4 blocks.
    __shared__ int segtot[64][4];
    __shared__ int segbase[64][4];
    __shared__ int ttot[4];
    int tid = threadIdx.x;
    int t = tid & 3, seg = tid >> 2;
    int s0 = bc[(seg * 4 + 0) * 4 + t];
    int s1 = bc[(seg * 4 + 1) * 4 + t];
    int s2 = bc[(seg * 4 + 2) * 4 + t];
    int s3 = bc[(seg * 4 + 3) * 4 + t];
    segtot[seg][t] = s0 + s1 + s2 + s3;
    __syncthreads();
    if (tid < 4) {
        int run = 0;
        for (int g = 0; g < 64; ++g) { segbase[g][tid] = run; run += segtot[g][tid]; }
        ttot[tid] = run;
        counts[tid] = run;
    }
    __syncthreads();
    if (tid == 0) {     // tile map: prefix over ceil(cnt_t/128)
        int s = 0;
        tmap[0] = 0;
        for (int u = 0; u < 4; ++u) { s += (ttot[u] + 127) >> 7; tmap[u + 1] = s; }
    }
    int toff = 0;
    for (int u = 0; u < 4; ++u) toff += (u < t) ? ttot[u] : 0;
    int run = toff + segbase[seg][t];
    base[(seg * 4 + 0) * 4 + t] = run; run += s0;
    base[(seg * 4 + 1) * 4 + t] = run; run += s1;
    base[(seg * 4 + 2) * 4 + t] = run; run += s2;
    base[(seg * 4 + 3) * 4 + t] = run;
}

__global__ __launch_bounds__(256) void scatter_kernel(const int* __restrict__ idx,
        const int* __restrict__ base, int* __restrict__ perm,
        const float* __restrict__ b2, float* __restrict__ out) {
    int tid = threadIdx.x;
    int i = blockIdx.x * 256 + tid;
    int t = idx[i];
    int lane = tid & 63, wave = tid >> 6;
    ull b0 = __ballot(t & 1);
    ull b1 = __ballot(t & 2);
    ull mask = ((t & 1) ? b0 : ~b0) & ((t & 2) ? b1 : ~b1);
    int rank = __popcll(mask & ((1ULL << lane) - 1ULL));
    __shared__ int lc[4][4];
    if (tid < 16) ((int*)lc)[tid] = 0;
    __syncthreads();
    if (rank == 0) lc[wave][t] = __popcll(mask);
    __syncthreads();
    int pre = 0;
#pragma unroll
    for (int w = 0; w < 4; ++w) pre += (w < wave) ? lc[w][t] : 0;
    perm[base[blockIdx.x * 4 + t] + pre + rank] = i;
    out[i] = b2[t];   // init: gemm epilogue atomically accumulates onto this
}

// ---------------- pipelined routed GEMM + fused epilogue (R5/R11 structure) ----------------
// 128x128 tile, BK=64, 4 waves (2x2), double-buffered LDS for A and B,
// raw s_barrier + counted vmcnt: A prefetched 2 K-tiles deep stays in flight
// across barriers. B via global_load_lds from pre-transposed bf16 Wt.
// Grid exact via tmap (2080 blocks). Epilogue: direct atomicAdd (8 adds/sample).
__global__ __launch_bounds__(256, 2) void gemm_pipe(
        const float* __restrict__ feat, const u16* __restrict__ Wt,
        const float* __restrict__ b1, const float* __restrict__ w2,
        const int* __restrict__ perm, const int* __restrict__ counts,
        const int* __restrict__ tmap, float* __restrict__ out) {
    __shared__ char smem[65536];   // abuf0 @0, abuf1 @16K, bbuf0 @32K, bbuf1 @48K

    int bx = blockIdx.x;
    int r8 = bx & 7, m8 = bx >> 3;
    int ct = m8 & 3;
    int tau = (m8 >> 2) * 8 + r8;       // 4 ct-siblings adjacent per XCD slot
    if (tau >= tmap[4]) return;
    int t = 0;
#pragma unroll
    for (int u = 0; u < 3; ++u) t += (tau >= tmap[u + 1]) ? 1 : 0;
    int tile_m = tau - tmap[t];
    int cnt = counts[t];
    int tilebase = tile_m * 128;
    int off_t = 0;
    for (int u = 0; u < t; ++u) off_t += counts[u];

    int tid = threadIdx.x;
    int lane = tid & 63, wave = tid >> 6;
    int wr = wave >> 1, wc = wave & 1;
    int hc0 = ct * 128;

    // A gather offsets: 8 rows/thread, 16 threads per row (f32x4 each)
    unsigned aoff[8];
#pragma unroll
    for (int i = 0; i < 8; ++i) {
        int r = tilebase + i * 16 + (tid >> 4);
        if (r > cnt - 1) r = cnt - 1;
        aoff[i] = (unsigned)perm[off_t + r] * ND + (tid & 15) * 4;
    }
    // B direct-to-LDS: linear dest + inverse-swizzled per-lane global source
    unsigned boff[4];
#pragma unroll
    for (int j = 0; j < 4; ++j) {
        int a = wave * 4096 + j * 1024 + lane * 16;
        int col = a >> 7, chunk = (a >> 4) & 7;
        boff[j] = (unsigned)((t * NH + hc0 + col) * ND + ((chunk ^ (col & 7)) * 8));
    }

    f32x4 acc[4][4];
#pragma unroll
    for (int a = 0; a < 4; ++a)
#pragma unroll
        for (int b = 0; b < 4; ++b) acc[a][b] = (f32x4){0.f, 0.f, 0.f, 0.f};

    f32x4 apf0[8], apf1[8];   // two named A staging sets (no runtime indexing)

    auto LOADA = [&](f32x4 (&arr)[8], int kt) {
#pragma unroll
        for (int i = 0; i < 8; ++i)
            arr[i] = *(const f32x4*)(feat + aoff[i] + kt * 64);
    };
    auto STAGE_B = [&](int kt, int buf) {
        char* dst = smem + 32768 + buf * 16384 + wave * 4096;
#pragma unroll
        for (int j = 0; j < 4; ++j)
            gload_lds16(Wt + boff[j] + kt * 64, dst + j * 1024);
    };
    auto WRITEA = [&](const f32x4 (&arr)[8], int buf) {
        char* ab = smem + buf * 16384;
#pragma unroll
        for (int i = 0; i < 8; ++i) {
            int row = i * 16 + (tid >> 4);
            u32x2 v;
            v.x = packbf(arr[i][0], arr[i][1]);
            v.y = packbf(arr[i][2], arr[i][3]);
            *(u32x2*)(ab + swz(row * 128 + (tid & 15) * 8)) = v;
        }
    };
    auto COMPUTE = [&](int buf) {
        char* ab = smem + buf * 16384;
        char* bb = smem + 32768 + buf * 16384;
#pragma unroll
        for (int ks = 0; ks < 2; ++ks) {
            int kbyte = ks * 64 + (lane >> 4) * 16;
            s16x8 af[4], bf[4];
#pragma unroll
            for (int f = 0; f < 4; ++f) {
                int rowA = wr * 64 + f * 16 + (lane & 15);
                af[f] = *(const s16x8*)(ab + swz(rowA * 128 + kbyte));
                int colB = wc * 64 + f * 16 + (lane & 15);
                bf[f] = *(const s16x8*)(bb + swz(colB * 128 + kbyte));
            }
#pragma unroll
            for (int fm = 0; fm < 4; ++fm)
#pragma unroll
                for (int fn = 0; fn < 4; ++fn)
                    acc[fm][fn] = __builtin_amdgcn_mfma_f32_16x16x32_bf16(
                        af[fm], bf[fn], acc[fm][fn], 0, 0, 0);
        }
    };

    // ---- prologue: Q=[B0:4, A0:8, A1:8] -> wait vmcnt(8) -> A0,B0 done ----
    STAGE_B(0, 0);
    SCHEDB;
    LOADA(apf0, 0);
    SCHEDB;
    LOADA(apf1, 1);
    SCHEDB;
    WAITVM(8);
    WRITEA(apf0, 0);
    WAITLGKM;
    __builtin_amdgcn_s_barrier();

    // ---- steady state: 2 tiles per loop body (static buffer indices) ----
#pragma unroll 1
    for (int kt = 0; kt < 18; kt += 2) {
        // even tile kt: compute buf0. In flight: A(kt+1):8
        STAGE_B(kt + 1, 1);                 // +4
        SCHEDB;
        LOADA(apf0, kt + 2);                // +8  -> Q=[A+1:8, B+1:4, A+2:8]
        SCHEDB;
        COMPUTE(0);
        WAITVM(12);                         // A(kt+1) done
        WRITEA(apf1, 1);
        WAITVM(8);                          // B(kt+1) landed; A(kt+2) in flight
        WAITLGKM;
        __builtin_amdgcn_s_barrier();
        // odd tile kt+1: compute buf1. In flight: A(kt+2):8
        STAGE_B(kt + 2, 0);
        SCHEDB;
        LOADA(apf1, kt + 3);
        SCHEDB;
        COMPUTE(1);
        WAITVM(12);                         // A(kt+2) done
        WRITEA(apf0, 0);
        WAITVM(8);                          // B(kt+2) landed; A(kt+3) in flight
        WAITLGKM;
        __builtin_amdgcn_s_barrier();
    }

    // ---- peel kt=18 (buf0), tile 19 arrives in apf1 ----
    STAGE_B(19, 1);                         // Q=[A19:8, B19:4]
    SCHEDB;
    COMPUTE(0);                             // tile 18
    WAITVM(4);                              // A19 done
    WRITEA(apf1, 1);
    WAITVM(0);                              // B19 landed
    WAITLGKM;
    __builtin_amdgcn_s_barrier();
    COMPUTE(1);                             // tile 19

    // ---- epilogue: +b1, exact GELU, *w2, reduce over this wave's 64 cols ----
    float part[4][4];
#pragma unroll
    for (int fm = 0; fm < 4; ++fm)
#pragma unroll
        for (int r = 0; r < 4; ++r) part[fm][r] = 0.f;
#pragma unroll
    for (int fn = 0; fn < 4; ++fn) {
        int h = hc0 + wc * 64 + fn * 16 + (lane & 15);
        float b1v = b1[t * NH + h];
        float w2v = w2[t * NH + h];
#pragma unroll
        for (int fm = 0; fm < 4; ++fm)
#pragma unroll
            for (int r = 0; r < 4; ++r) {
                float v = acc[fm][fn][r] + b1v;
                part[fm][r] += gelu_exact(v) * w2v;
            }
    }
#pragma unroll
    for (int m = 1; m <= 8; m <<= 1)
#pragma unroll
        for (int fm = 0; fm < 4; ++fm)
#pragma unroll
            for (int r = 0; r < 4; ++r)
                part[fm][r] += __shfl_xor(part[fm][r], m, 64);

    if ((lane & 15) == 0) {
#pragma unroll
        for (int fm = 0; fm < 4; ++fm)
#pragma unroll
            for (int r = 0; r < 4; ++r) {
                int row = wr * 64 + fm * 16 + (lane >> 4) * 4 + r;
                int gr = tilebase + row;
                if (gr < cnt)
                    atomicAdd(&out[perm[off_t + gr]], part[fm][r]);
            }
    }
}

// ---------------- fallback (no-Wt) path: R3 LDS kernel, strided f32 B ----------------
__global__ __launch_bounds__(256, 2) void gemm_fallback(
        const float* __restrict__ feat, const float* __restrict__ W1,
        const float* __restrict__ b1, const float* __restrict__ w2,
        const int* __restrict__ perm, const int* __restrict__ counts,
        float* __restrict__ out) {
    __shared__ char smem[32768];
    int bx = blockIdx.x;
    int r8 = bx & 7, m8 = bx >> 3;
    int ct = m8 & 3, q = m8 >> 2;
    int g = q * 8 + r8;
    int t = g >> 9, tile_m = g & 511;
    int cnt = counts[t];
    int tilebase = tile_m * 128;
    if (tilebase >= cnt) return;
    int off_t = 0;
    for (int u = 0; u < t; ++u) off_t += counts[u];

    int tid = threadIdx.x;
    int lane = tid & 63, wave = tid >> 6;
    int wr = wave >> 1, wc = wave & 1;
    int hc0 = ct * 128;

    unsigned aoff[8];
#pragma unroll
    for (int i = 0; i < 8; ++i) {
        int r = tilebase + i * 16 + (tid >> 4);
        if (r > cnt - 1) r = cnt - 1;
        int s = perm[off_t + r];
        aoff[i] = (unsigned)s * ND + (tid & 15) * 4;
    }
    f32x4 acc[4][4];
#pragma unroll
    for (int a = 0; a < 4; ++a)
#pragma unroll
        for (int b = 0; b < 4; ++b) acc[a][b] = (f32x4){0.f, 0.f, 0.f, 0.f};
    f32x4 apf[8];
    int cpair = (tid & 63) * 2;
    int kkbase = tid >> 6;
    const float* wbase = W1 + (size_t)t * ND * NH + hc0 + cpair;
    f32x2 bpf[4][4];
    auto LOADA = [&](int k0) {
#pragma unroll
        for (int i = 0; i < 8; ++i)
            apf[i] = *(const f32x4*)(feat + aoff[i] + k0);
    };
    auto LOADB = [&](int k0) {
#pragma unroll
        for (int qq = 0; qq < 4; ++qq) {
            int d = k0 + (kkbase + qq * 4) * 4;
#pragma unroll
            for (int e = 0; e < 4; ++e)
                bpf[qq][e] = *(const f32x2*)(wbase + (size_t)(d + e) * NH);
        }
    };
    auto WRITEA = [&]() {
#pragma unroll
        for (int i = 0; i < 8; ++i) {
            int row = i * 16 + (tid >> 4);
            u32x2 v;
            v.x = packbf(apf[i][0], apf[i][1]);
            v.y = packbf(apf[i][2], apf[i][3]);
            *(u32x2*)(smem + swz(row * 128 + (tid & 15) * 8)) = v;
        }
    };
    auto WRITEB = [&]() {
#pragma unroll
        for (int qq = 0; qq < 4; ++qq) {
            int kk = kkbase + qq * 4;
#pragma unroll
            for (int j = 0; j < 2; ++j) {
                u32x2 v;
                v.x = packbf(bpf[qq][0][j], bpf[qq][1][j]);
                v.y = packbf(bpf[qq][2][j], bpf[qq][3][j]);
                *(u32x2*)(smem + 16384 + swz((cpair + j) * 128 + kk * 8)) = v;
            }
        }
    };
    auto COMPUTE_KS = [&](int ks) {
        int kbyte = ks * 64 + (lane >> 4) * 16;
        s16x8 af[4], bf[4];
#pragma unroll
        for (int f = 0; f < 4; ++f) {
            int rowA = wr * 64 + f * 16 + (lane & 15);
            af[f] = *(const s16x8*)(smem + swz(rowA * 128 + kbyte));
            int colB = wc * 64 + f * 16 + (lane & 15);
            bf[f] = *(const s16x8*)(smem + 16384 + swz(colB * 128 + kbyte));
        }
#pragma unroll
        for (int fm = 0; fm < 4; ++fm)
#pragma unroll
            for (int fn = 0; fn < 4; ++fn)
                acc[fm][fn] = __builtin_amdgcn_mfma_f32_16x16x32_bf16(
                    af[fm], bf[fn], acc[fm][fn], 0, 0, 0);
    };
    LOADA(0); LOADB(0);
    WRITEA(); WRITEB();
    __syncthreads();
#pragma unroll 1
    for (int kt = 0; kt < 20; ++kt) {
        bool nxt = (kt + 1 < 20);
        if (nxt) LOADA((kt + 1) * 64);
        COMPUTE_KS(0);
        if (nxt) LOADB((kt + 1) * 64);
        COMPUTE_KS(1);
        if (nxt) {
            __syncthreads();
            WRITEA(); WRITEB();
            __syncthreads();
        }
    }
    float part[4][4];
#pragma unroll
    for (int fm = 0; fm < 4; ++fm)
#pragma unroll
        for (int r = 0; r < 4; ++r) part[fm][r] = 0.f;
#pragma unroll
    for (int fn = 0; fn < 4; ++fn) {
        int h = hc0 + wc * 64 + fn * 16 + (lane & 15);
        float b1v = b1[t * NH + h];
        float w2v = w2[t * NH + h];
#pragma unroll
        for (int fm = 0; fm < 4; ++fm)
#pragma unroll
            for (int r = 0; r < 4; ++r) {
                float v = acc[fm][fn][r] + b1v;
                part[fm][r] += gelu_exact(v) * w2v;
            }
    }
#pragma unroll
    for (int m = 1; m <= 8; m <<= 1)
#pragma unroll
        for (int fm = 0; fm < 4; ++fm)
#pragma unroll
            for (int r = 0; r < 4; ++r)
                part[fm][r] += __shfl_xor(part[fm][r], m, 64);
    if ((lane & 15) == 0) {
#pragma unroll
        for (int fm = 0; fm < 4; ++fm)
#pragma unroll
            for (int r = 0; r < 4; ++r) {
                int row = wr * 64 + fm * 16 + (lane >> 4) * 4 + r;
                int gr = tilebase + row;
                if (gr < cnt)
                    atomicAdd(&out[perm[off_t + gr]], part[fm][r]);
            }
    }
}

extern "C" void kernel_launch(void* const* d_in, const int* in_sizes, int n_in,
                              void* d_out, int out_size, void* d_ws, size_t ws_size,
                              hipStream_t stream) {
    (void)in_sizes; (void)n_in; (void)out_size;
    const float* feat = (const float*)d_in[0];
    const int*   idx  = (const int*)d_in[1];
    const float* W1   = (const float*)d_in[2];
    const float* b1   = (const float*)d_in[3];
    const float* w2   = (const float*)d_in[4];
    const float* b2   = (const float*)d_in[5];
    float* out = (float*)d_out;

    char* ws = (char*)d_ws;
    int* counts  = (int*)ws;                                   // 64 B
    int* bc      = (int*)(ws + 64);                            // 4 KiB
    int* base    = (int*)(ws + 64 + 4096);                     // 4 KiB
    int* tmap    = (int*)(ws + 64 + 8192);                     // 64 B
    int* perm    = (int*)(ws + 128 + 8192);                    // 256 KiB
    u16* Wt = (u16*)(ws + 128 + 8192 + (size_t)NB * 4);        // 5.25 MiB
    size_t need = 128 + 8192 + (size_t)NB * 4 + (size_t)NT * ND * NH * 2;
    int use_wt = (ws_size >= need) ? 1 : 0;

    if (use_wt)
        transpose_kernel<<<NT * 8 * 20, 256, 0, stream>>>(W1, Wt);
    count_kernel<<<NB / 256, 256, 0, stream>>>(idx, bc);
    scan_kernel<<<1, 256, 0, stream>>>(bc, counts, base, tmap);
    scatter_kernel<<<NB / 256, 256, 0, stream>>>(idx, base, perm, b2, out);
    if (use_wt)
        gemm_pipe<<<2080, 256, 0, stream>>>(feat, Wt, b1, w2, perm, counts, tmap, out);
    else
        gemm_fallback<<<8192, 256, 0, stream>>>(feat, W1, b1, w2, perm, counts, out);
}

// Round 13
// 210.853 us; speedup vs baseline: 1.0413x; 1.0413x over previous
//
#include <hip/hip_runtime.h>
#include <math.h>

#define NB 65536
#define ND 1280
#define NH 512
#define NT 4

typedef float f32x4 __attribute__((ext_vector_type(4)));
typedef float f32x2 __attribute__((ext_vector_type(2)));
typedef short s16x8 __attribute__((ext_vector_type(8)));
typedef unsigned int u32x2 __attribute__((ext_vector_type(2)));
typedef unsigned int u32x4 __attribute__((ext_vector_type(4)));
typedef unsigned long long ull;
typedef unsigned short u16;

static __device__ __forceinline__ unsigned f2bf1(float x) {
    union { float f; unsigned u; } v; v.f = x;
    return (v.u + 0x7fffu + ((v.u >> 16) & 1u)) >> 16;   // RNE f32 -> bf16 bits
}
static __device__ __forceinline__ unsigned packbf(float a, float b) {
    return f2bf1(a) | (f2bf1(b) << 16);
}
static __device__ __forceinline__ int swz(int a) {
    return a ^ (((a >> 7) & 7) << 4);
}
static __device__ __forceinline__ float gelu_exact(float x) {
    return 0.5f * x * (1.0f + erff(x * 0.70710678118654752f));
}
static __device__ __forceinline__ void gload_lds16(const void* g, void* l) {
    __builtin_amdgcn_global_load_lds(
        (const __attribute__((address_space(1))) unsigned int*)g,
        (__attribute__((address_space(3))) unsigned int*)l, 16, 0, 0);
}

#define SCHEDB __builtin_amdgcn_sched_barrier(0)
#define WAITVM(N) do { asm volatile("s_waitcnt vmcnt(" #N ")" ::: "memory"); SCHEDB; } while (0)
#define WAITLGKM do { asm volatile("s_waitcnt lgkmcnt(0)" ::: "memory"); SCHEDB; } while (0)

// ---------------- W1 transpose+convert: [t][d][h] f32 -> [t][h][d] bf16 ----------------
__global__ __launch_bounds__(256) void transpose_kernel(const float* __restrict__ W1,
                                                        u16* __restrict__ Wt) {
    __shared__ float tile[64][65];
    int b = blockIdx.x;                 // 4 * 8 * 20 blocks
    int dt = b % 20; int r = b / 20; int ht = r & 7; int t = r >> 3;
    int d0 = dt * 64, h0 = ht * 64;
    int tid = threadIdx.x;
    const float* src = W1 + ((size_t)t * ND + d0) * NH + h0;
#pragma unroll
    for (int it = 0; it < 16; ++it) {
        int dl = it * 4 + (tid >> 6);
        tile[dl][tid & 63] = src[(size_t)dl * NH + (tid & 63)];
    }
    __syncthreads();
    int hl = tid >> 2, ds = (tid & 3) * 16;
    unsigned pk[8];
#pragma unroll
    for (int j = 0; j < 8; ++j)
        pk[j] = packbf(tile[ds + 2 * j][hl], tile[ds + 2 * j + 1][hl]);
    u16* dst = Wt + ((size_t)(t * NH + h0 + hl)) * ND + d0 + ds;
    *(u32x4*)dst = (u32x4){pk[0], pk[1], pk[2], pk[3]};
    *(u32x4*)(dst + 8) = (u32x4){pk[4], pk[5], pk[6], pk[7]};
}

// ---------------- bucketing (atomic-free counting sort) ----------------
__global__ __launch_bounds__(256) void count_kernel(const int* __restrict__ idx,
                                                    int* __restrict__ bc) {
    int tid = threadIdx.x;
    int i = blockIdx.x * 256 + tid;
    int t = idx[i];
    int lane = tid & 63, wave = tid >> 6;
    ull b0 = __ballot(t & 1);
    ull b1 = __ballot(t & 2);
    ull mask = ((t & 1) ? b0 : ~b0) & ((t & 2) ? b1 : ~b1);
    int rank = __popcll(mask & ((1ULL << lane) - 1ULL));
    __shared__ int lc[4][4];
    if (tid < 16) ((int*)lc)[tid] = 0;
    __syncthreads();
    if (rank == 0) lc[wave][t] = __popcll(mask);
    __syncthreads();
    if (tid < 4)
        bc[blockIdx.x * 4 + tid] = lc[0][tid] + lc[1][tid] + lc[2][tid] + lc[3][tid];
}

__global__ __launch_bounds__(256) void scan_kernel(const int* __restrict__ bc,
        int* __restrict__ counts, int* __restrict__ base, int* __restrict__ tmap) {
    // 256 threads -> (seg = tid>>2 in 0..63, t = tid&3); each seg covers 4 blocks.
    __shared__ int segtot[64][4];
    __shared__ int segbase[64][4];
    __shared__ int ttot[4];
    int tid = threadIdx.x;
    int t = tid & 3, seg = tid >> 2;
    int s0 = bc[(seg * 4 + 0) * 4 + t];
    int s1 = bc[(seg * 4 + 1) * 4 + t];
    int s2 = bc[(seg * 4 + 2) * 4 + t];
    int s3 = bc[(seg * 4 + 3) * 4 + t];
    segtot[seg][t] = s0 + s1 + s2 + s3;
    __syncthreads();
    if (tid < 4) {
        int run = 0;
        for (int g = 0; g < 64; ++g) { segbase[g][tid] = run; run += segtot[g][tid]; }
        ttot[tid] = run;
        counts[tid] = run;
    }
    __syncthreads();
    if (tid == 0) {     // tile map: prefix over ceil(cnt_t/128)
        int s = 0;
        tmap[0] = 0;
        for (int u = 0; u < 4; ++u) { s += (ttot[u] + 127) >> 7; tmap[u + 1] = s; }
    }
    int toff = 0;
    for (int u = 0; u < 4; ++u) toff += (u < t) ? ttot[u] : 0;
    int run = toff + segbase[seg][t];
    base[(seg * 4 + 0) * 4 + t] = run; run += s0;
    base[(seg * 4 + 1) * 4 + t] = run; run += s1;
    base[(seg * 4 + 2) * 4 + t] = run; run += s2;
    base[(seg * 4 + 3) * 4 + t] = run;
}

__global__ __launch_bounds__(256) void scatter_kernel(const int* __restrict__ idx,
        const int* __restrict__ base, int* __restrict__ perm,
        const float* __restrict__ b2, float* __restrict__ out) {
    int tid = threadIdx.x;
    int i = blockIdx.x * 256 + tid;
    int t = idx[i];
    int lane = tid & 63, wave = tid >> 6;
    ull b0 = __ballot(t & 1);
    ull b1 = __ballot(t & 2);
    ull mask = ((t & 1) ? b0 : ~b0) & ((t & 2) ? b1 : ~b1);
    int rank = __popcll(mask & ((1ULL << lane) - 1ULL));
    __shared__ int lc[4][4];
    if (tid < 16) ((int*)lc)[tid] = 0;
    __syncthreads();
    if (rank == 0) lc[wave][t] = __popcll(mask);
    __syncthreads();
    int pre = 0;
#pragma unroll
    for (int w = 0; w < 4; ++w) pre += (w < wave) ? lc[w][t] : 0;
    perm[base[blockIdx.x * 4 + t] + pre + rank] = i;
    out[i] = b2[t];   // init for atomic fallback path
}

// ---------------- pipelined routed GEMM + fused epilogue (R5/R11 structure) ----------------
// 128x128 tile, BK=64, 4 waves (2x2), double-buffered LDS for A and B,
// raw s_barrier + counted vmcnt: A prefetched 2 K-tiles deep stays in flight
// across barriers. B via global_load_lds from pre-transposed bf16 Wt.
// Grid is exact via tmap (2080 blocks), no no-op dispatches.
__global__ __launch_bounds__(256, 2) void gemm_pipe(
        const float* __restrict__ feat, const u16* __restrict__ Wt,
        const float* __restrict__ b1, const float* __restrict__ w2,
        const int* __restrict__ perm, const int* __restrict__ counts,
        const int* __restrict__ tmap,
        float* __restrict__ partials, float* __restrict__ out, int use_partials) {
    __shared__ char smem[65536];   // abuf0 @0, abuf1 @16K, bbuf0 @32K, bbuf1 @48K

    int bx = blockIdx.x;
    int r8 = bx & 7, m8 = bx >> 3;
    int ct = m8 & 3;
    int tau = (m8 >> 2) * 8 + r8;       // 4 ct-siblings adjacent per XCD slot
    if (tau >= tmap[4]) return;
    int t = 0;
#pragma unroll
    for (int u = 0; u < 3; ++u) t += (tau >= tmap[u + 1]) ? 1 : 0;
    int tile_m = tau - tmap[t];
    int cnt = counts[t];
    int tilebase = tile_m * 128;
    int off_t = 0;
    for (int u = 0; u < t; ++u) off_t += counts[u];

    int tid = threadIdx.x;
    int lane = tid & 63, wave = tid >> 6;
    int wr = wave >> 1, wc = wave & 1;
    int hc0 = ct * 128;

    // A gather offsets: 8 rows/thread, 16 threads per row (f32x4 each)
    unsigned aoff[8];
#pragma unroll
    for (int i = 0; i < 8; ++i) {
        int r = tilebase + i * 16 + (tid >> 4);
        if (r > cnt - 1) r = cnt - 1;
        aoff[i] = (unsigned)perm[off_t + r] * ND + (tid & 15) * 4;
    }
    // B direct-to-LDS: linear dest + inverse-swizzled per-lane global source
    unsigned boff[4];
#pragma unroll
    for (int j = 0; j < 4; ++j) {
        int a = wave * 4096 + j * 1024 + lane * 16;
        int col = a >> 7, chunk = (a >> 4) & 7;
        boff[j] = (unsigned)((t * NH + hc0 + col) * ND + ((chunk ^ (col & 7)) * 8));
    }

    f32x4 acc[4][4];
#pragma unroll
    for (int a = 0; a < 4; ++a)
#pragma unroll
        for (int b = 0; b < 4; ++b) acc[a][b] = (f32x4){0.f, 0.f, 0.f, 0.f};

    f32x4 apf0[8], apf1[8];   // two named A staging sets (no runtime indexing)

    auto LOADA = [&](f32x4 (&arr)[8], int kt) {
#pragma unroll
        for (int i = 0; i < 8; ++i)
            arr[i] = *(const f32x4*)(feat + aoff[i] + kt * 64);
    };
    auto STAGE_B = [&](int kt, int buf) {
        char* dst = smem + 32768 + buf * 16384 + wave * 4096;
#pragma unroll
        for (int j = 0; j < 4; ++j)
            gload_lds16(Wt + boff[j] + kt * 64, dst + j * 1024);
    };
    auto WRITEA = [&](const f32x4 (&arr)[8], int buf) {
        char* ab = smem + buf * 16384;
#pragma unroll
        for (int i = 0; i < 8; ++i) {
            int row = i * 16 + (tid >> 4);
            u32x2 v;
            v.x = packbf(arr[i][0], arr[i][1]);
            v.y = packbf(arr[i][2], arr[i][3]);
            *(u32x2*)(ab + swz(row * 128 + (tid & 15) * 8)) = v;
        }
    };
    auto COMPUTE = [&](int buf) {
        char* ab = smem + buf * 16384;
        char* bb = smem + 32768 + buf * 16384;
#pragma unroll
        for (int ks = 0; ks < 2; ++ks) {
            int kbyte = ks * 64 + (lane >> 4) * 16;
            s16x8 af[4], bf[4];
#pragma unroll
            for (int f = 0; f < 4; ++f) {
                int rowA = wr * 64 + f * 16 + (lane & 15);
                af[f] = *(const s16x8*)(ab + swz(rowA * 128 + kbyte));
                int colB = wc * 64 + f * 16 + (lane & 15);
                bf[f] = *(const s16x8*)(bb + swz(colB * 128 + kbyte));
            }
#pragma unroll
            for (int fm = 0; fm < 4; ++fm)
#pragma unroll
                for (int fn = 0; fn < 4; ++fn)
                    acc[fm][fn] = __builtin_amdgcn_mfma_f32_16x16x32_bf16(
                        af[fm], bf[fn], acc[fm][fn], 0, 0, 0);
        }
    };

    // ---- prologue: Q=[B0:4, A0:8, A1:8] -> wait vmcnt(8) -> A0,B0 done ----
    STAGE_B(0, 0);
    SCHEDB;
    LOADA(apf0, 0);
    SCHEDB;
    LOADA(apf1, 1);
    SCHEDB;
    WAITVM(8);
    WRITEA(apf0, 0);
    WAITLGKM;
    __builtin_amdgcn_s_barrier();

    // ---- steady state: 2 tiles per loop body (static buffer indices) ----
#pragma unroll 1
    for (int kt = 0; kt < 18; kt += 2) {
        // even tile kt: compute buf0. In flight: A(kt+1):8
        STAGE_B(kt + 1, 1);                 // +4
        SCHEDB;
        LOADA(apf0, kt + 2);                // +8  -> Q=[A+1:8, B+1:4, A+2:8]
        SCHEDB;
        COMPUTE(0);
        WAITVM(12);                         // A(kt+1) done
        WRITEA(apf1, 1);
        WAITVM(8);                          // B(kt+1) landed; A(kt+2) in flight
        WAITLGKM;
        __builtin_amdgcn_s_barrier();
        // odd tile kt+1: compute buf1. In flight: A(kt+2):8
        STAGE_B(kt + 2, 0);
        SCHEDB;
        LOADA(apf1, kt + 3);
        SCHEDB;
        COMPUTE(1);
        WAITVM(12);                         // A(kt+2) done
        WRITEA(apf0, 0);
        WAITVM(8);                          // B(kt+2) landed; A(kt+3) in flight
        WAITLGKM;
        __builtin_amdgcn_s_barrier();
    }

    // ---- peel kt=18 (buf0), tile 19 arrives in apf1 ----
    STAGE_B(19, 1);                         // Q=[A19:8, B19:4]
    SCHEDB;
    COMPUTE(0);                             // tile 18
    WAITVM(4);                              // A19 done
    WRITEA(apf1, 1);
    WAITVM(0);                              // B19 landed
    WAITLGKM;
    __builtin_amdgcn_s_barrier();
    COMPUTE(1);                             // tile 19

    // ---- epilogue: +b1, exact GELU, *w2, reduce over this wave's 64 cols ----
    float part[4][4];
#pragma unroll
    for (int fm = 0; fm < 4; ++fm)
#pragma unroll
        for (int r = 0; r < 4; ++r) part[fm][r] = 0.f;
#pragma unroll
    for (int fn = 0; fn < 4; ++fn) {
        int h = hc0 + wc * 64 + fn * 16 + (lane & 15);
        float b1v = b1[t * NH + h];
        float w2v = w2[t * NH + h];
#pragma unroll
        for (int fm = 0; fm < 4; ++fm)
#pragma unroll
            for (int r = 0; r < 4; ++r) {
                float v = acc[fm][fn][r] + b1v;
                part[fm][r] += gelu_exact(v) * w2v;
            }
    }
#pragma unroll
    for (int m = 1; m <= 8; m <<= 1)
#pragma unroll
        for (int fm = 0; fm < 4; ++fm)
#pragma unroll
            for (int r = 0; r < 4; ++r)
                part[fm][r] += __shfl_xor(part[fm][r], m, 64);

    if ((lane & 15) == 0) {
        int slot = ct * 2 + wc;
#pragma unroll
        for (int fm = 0; fm < 4; ++fm)
#pragma unroll
            for (int r = 0; r < 4; ++r) {
                int row = wr * 64 + fm * 16 + (lane >> 4) * 4 + r;
                int gr = tilebase + row;
                if (gr < cnt) {
                    int s = perm[off_t + gr];
                    if (use_partials)
                        partials[(size_t)s * 8 + slot] = part[fm][r];
                    else
                        atomicAdd(&out[s], part[fm][r]);
                }
            }
    }
}

// ---------------- fallback (no-Wt) path: R3 LDS kernel, strided f32 B ----------------
__global__ __launch_bounds__(256, 2) void gemm_fallback(
        const float* __restrict__ feat, const float* __restrict__ W1,
        const float* __restrict__ b1, const float* __restrict__ w2,
        const int* __restrict__ perm, const int* __restrict__ counts,
        float* __restrict__ partials, float* __restrict__ out, int use_partials) {
    __shared__ char smem[32768];
    int bx = blockIdx.x;
    int r8 = bx & 7, m8 = bx >> 3;
    int ct = m8 & 3, q = m8 >> 2;
    int g = q * 8 + r8;
    int t = g >> 9, tile_m = g & 511;
    int cnt = counts[t];
    int tilebase = tile_m * 128;
    if (tilebase >= cnt) return;
    int off_t = 0;
    for (int u = 0; u < t; ++u) off_t += counts[u];

    int tid = threadIdx.x;
    int lane = tid & 63, wave = tid >> 6;
    int wr = wave >> 1, wc = wave & 1;
    int hc0 = ct * 128;

    unsigned aoff[8];
#pragma unroll
    for (int i = 0; i < 8; ++i) {
        int r = tilebase + i * 16 + (tid >> 4);
        if (r > cnt - 1) r = cnt - 1;
        int s = perm[off_t + r];
        aoff[i] = (unsigned)s * ND + (tid & 15) * 4;
    }
    f32x4 acc[4][4];
#pragma unroll
    for (int a = 0; a < 4; ++a)
#pragma unroll
        for (int b = 0; b < 4; ++b) acc[a][b] = (f32x4){0.f, 0.f, 0.f, 0.f};
    f32x4 apf[8];
    int cpair = (tid & 63) * 2;
    int kkbase = tid >> 6;
    const float* wbase = W1 + (size_t)t * ND * NH + hc0 + cpair;
    f32x2 bpf[4][4];
    auto LOADA = [&](int k0) {
#pragma unroll
        for (int i = 0; i < 8; ++i)
            apf[i] = *(const f32x4*)(feat + aoff[i] + k0);
    };
    auto LOADB = [&](int k0) {
#pragma unroll
        for (int qq = 0; qq < 4; ++qq) {
            int d = k0 + (kkbase + qq * 4) * 4;
#pragma unroll
            for (int e = 0; e < 4; ++e)
                bpf[qq][e] = *(const f32x2*)(wbase + (size_t)(d + e) * NH);
        }
    };
    auto WRITEA = [&]() {
#pragma unroll
        for (int i = 0; i < 8; ++i) {
            int row = i * 16 + (tid >> 4);
            u32x2 v;
            v.x = packbf(apf[i][0], apf[i][1]);
            v.y = packbf(apf[i][2], apf[i][3]);
            *(u32x2*)(smem + swz(row * 128 + (tid & 15) * 8)) = v;
        }
    };
    auto WRITEB = [&]() {
#pragma unroll
        for (int qq = 0; qq < 4; ++qq) {
            int kk = kkbase + qq * 4;
#pragma unroll
            for (int j = 0; j < 2; ++j) {
                u32x2 v;
                v.x = packbf(bpf[qq][0][j], bpf[qq][1][j]);
                v.y = packbf(bpf[qq][2][j], bpf[qq][3][j]);
                *(u32x2*)(smem + 16384 + swz((cpair + j) * 128 + kk * 8)) = v;
            }
        }
    };
    auto COMPUTE_KS = [&](int ks) {
        int kbyte = ks * 64 + (lane >> 4) * 16;
        s16x8 af[4], bf[4];
#pragma unroll
        for (int f = 0; f < 4; ++f) {
            int rowA = wr * 64 + f * 16 + (lane & 15);
            af[f] = *(const s16x8*)(smem + swz(rowA * 128 + kbyte));
            int colB = wc * 64 + f * 16 + (lane & 15);
            bf[f] = *(const s16x8*)(smem + 16384 + swz(colB * 128 + kbyte));
        }
#pragma unroll
        for (int fm = 0; fm < 4; ++fm)
#pragma unroll
            for (int fn = 0; fn < 4; ++fn)
                acc[fm][fn] = __builtin_amdgcn_mfma_f32_16x16x32_bf16(
                    af[fm], bf[fn], acc[fm][fn], 0, 0, 0);
    };
    LOADA(0); LOADB(0);
    WRITEA(); WRITEB();
    __syncthreads();
#pragma unroll 1
    for (int kt = 0; kt < 20; ++kt) {
        bool nxt = (kt + 1 < 20);
        if (nxt) LOADA((kt + 1) * 64);
        COMPUTE_KS(0);
        if (nxt) LOADB((kt + 1) * 64);
        COMPUTE_KS(1);
        if (nxt) {
            __syncthreads();
            WRITEA(); WRITEB();
            __syncthreads();
        }
    }
    float part[4][4];
#pragma unroll
    for (int fm = 0; fm < 4; ++fm)
#pragma unroll
        for (int r = 0; r < 4; ++r) part[fm][r] = 0.f;
#pragma unroll
    for (int fn = 0; fn < 4; ++fn) {
        int h = hc0 + wc * 64 + fn * 16 + (lane & 15);
        float b1v = b1[t * NH + h];
        float w2v = w2[t * NH + h];
#pragma unroll
        for (int fm = 0; fm < 4; ++fm)
#pragma unroll
            for (int r = 0; r < 4; ++r) {
                float v = acc[fm][fn][r] + b1v;
                part[fm][r] += gelu_exact(v) * w2v;
            }
    }
#pragma unroll
    for (int m = 1; m <= 8; m <<= 1)
#pragma unroll
        for (int fm = 0; fm < 4; ++fm)
#pragma unroll
            for (int r = 0; r < 4; ++r)
                part[fm][r] += __shfl_xor(part[fm][r], m, 64);
    if ((lane & 15) == 0) {
        int slot = ct * 2 + wc;
#pragma unroll
        for (int fm = 0; fm < 4; ++fm)
#pragma unroll
            for (int r = 0; r < 4; ++r) {
                int row = wr * 64 + fm * 16 + (lane >> 4) * 4 + r;
                int gr = tilebase + row;
                if (gr < cnt) {
                    int s = perm[off_t + gr];
                    if (use_partials)
                        partials[(size_t)s * 8 + slot] = part[fm][r];
                    else
                        atomicAdd(&out[s], part[fm][r]);
                }
            }
    }
}

__global__ __launch_bounds__(256) void reduce_kernel(const float* __restrict__ partials,
        const int* __restrict__ idx, const float* __restrict__ b2,
        float* __restrict__ out) {
    int i = blockIdx.x * 256 + threadIdx.x;
    const float* p = partials + (size_t)i * 8;
    float s = b2[idx[i]];
#pragma unroll
    for (int j = 0; j < 8; ++j) s += p[j];
    out[i] = s;
}

extern "C" void kernel_launch(void* const* d_in, const int* in_sizes, int n_in,
                              void* d_out, int out_size, void* d_ws, size_t ws_size,
                              hipStream_t stream) {
    (void)in_sizes; (void)n_in; (void)out_size;
    const float* feat = (const float*)d_in[0];
    const int*   idx  = (const int*)d_in[1];
    const float* W1   = (const float*)d_in[2];
    const float* b1   = (const float*)d_in[3];
    const float* w2   = (const float*)d_in[4];
    const float* b2   = (const float*)d_in[5];
    float* out = (float*)d_out;

    char* ws = (char*)d_ws;
    int* counts  = (int*)ws;                                   // 64 B
    int* bc      = (int*)(ws + 64);                            // 4 KiB
    int* base    = (int*)(ws + 64 + 4096);                     // 4 KiB
    int* tmap    = (int*)(ws + 64 + 8192);                     // 64 B
    int* perm    = (int*)(ws + 128 + 8192);                    // 256 KiB
    float* partials = (float*)(ws + 128 + 8192 + (size_t)NB * 4);       // 2 MiB
    u16* Wt = (u16*)(ws + 128 + 8192 + (size_t)NB * 4 + (size_t)NB * 32); // 5.25 MiB
    size_t need_part = 128 + 8192 + (size_t)NB * 4 + (size_t)NB * 32;
    size_t need_full = need_part + (size_t)NT * ND * NH * 2;
    int use_partials = (ws_size >= need_part) ? 1 : 0;
    int use_wt = (ws_size >= need_full) ? 1 : 0;

    if (use_wt)
        transpose_kernel<<<NT * 8 * 20, 256, 0, stream>>>(W1, Wt);
    count_kernel<<<NB / 256, 256, 0, stream>>>(idx, bc);
    scan_kernel<<<1, 256, 0, stream>>>(bc, counts, base, tmap);
    scatter_kernel<<<NB / 256, 256, 0, stream>>>(idx, base, perm, b2, out);
    if (use_wt)
        gemm_pipe<<<2080, 256, 0, stream>>>(feat, Wt, b1, w2, perm, counts, tmap,
                                            partials, out, use_partials);
    else
        gemm_fallback<<<8192, 256, 0, stream>>>(feat, W1, b1, w2, perm, counts,
                                                partials, out, use_partials);
    if (use_partials)
        reduce_kernel<<<NB / 256, 256, 0, stream>>>(partials, idx, b2, out);
}